// Round 10
// baseline (311.944 us; speedup 1.0000x reference)
//
#include <hip/hip_runtime.h>
#include <hip/hip_bf16.h>

#define N_NODES 50000
#define N_EDGES 600000
#define IN_DIM 128
#define HID 256
#define OUT_DIM 3

#define M_PAD 50048  // 391 blocks * 128 rows

#define SCAN_B 256
#define SCAN_NB ((N_NODES + SCAN_B - 1) / SCAN_B)  // 196

typedef __bf16 bf16x8 __attribute__((ext_vector_type(8)));
typedef float f32x4 __attribute__((ext_vector_type(4)));

static __device__ __forceinline__ unsigned short f2b(float f) {
    union { float f; unsigned u; } u; u.f = f;
    unsigned r = u.u + 0x7fffu + ((u.u >> 16) & 1u);  // round-to-nearest-even
    return (unsigned short)(r >> 16);
}
static __device__ __forceinline__ float b2f(unsigned short b) {
    union { unsigned u; float f; } u; u.u = ((unsigned)b) << 16;
    return u.f;
}

// MFMA-fragment ("swizzled") panel layout, K columns:
// tiles of 16 rows x 32 k; tile(tr=r>>4, tk=k>>5) at ((tr*(K/32)+tk)*512) elems;
// element (r,k) within tile at ((k>>3)&3)*128 + (r&15)*8 + (k&7).
// A wave's mfma fragment (one tile) = contiguous 1KB, lane l at tile_base + l*8.
static __device__ __forceinline__ size_t swz(int r, int k, int K) {
    return (((size_t)((r >> 4) * (K >> 5) + (k >> 5))) << 9)
         + ((((k >> 3) & 3) * 16 + (r & 15)) << 3) + (k & 7);
}

// ---------------- CSR build ----------------

__global__ void count_deg_kernel(const int* __restrict__ dst, int* __restrict__ counts) {
    int e = blockIdx.x * blockDim.x + threadIdx.x;
    if (e < N_EDGES) atomicAdd(&counts[dst[e]], 1);
}

__global__ __launch_bounds__(256) void block_sum_kernel(const int* __restrict__ counts,
                                                        int* __restrict__ partial) {
    int node = blockIdx.x * SCAN_B + threadIdx.x;
    int v = (node < N_NODES) ? counts[node] : 0;
#pragma unroll
    for (int off = 32; off > 0; off >>= 1) v += __shfl_down(v, off);
    __shared__ int ws[4];
    if ((threadIdx.x & 63) == 0) ws[threadIdx.x >> 6] = v;
    __syncthreads();
    if (threadIdx.x == 0) partial[blockIdx.x] = ws[0] + ws[1] + ws[2] + ws[3];
}

__global__ __launch_bounds__(256) void scan_partial_kernel(int* __restrict__ partial) {
    __shared__ int s[SCAN_B];
    int t = threadIdx.x;
    int v = (t < SCAN_NB) ? partial[t] : 0;
    s[t] = v;
    __syncthreads();
    for (int off = 1; off < SCAN_B; off <<= 1) {
        int u = (t >= off) ? s[t - off] : 0;
        __syncthreads();
        s[t] += u;
        __syncthreads();
    }
    if (t < SCAN_NB) partial[t] = s[t] - v;  // exclusive
}

__global__ __launch_bounds__(256) void write_rowptr_kernel(const int* __restrict__ counts,
                                                           const int* __restrict__ partial,
                                                           int* __restrict__ row_ptr) {
    __shared__ int s[SCAN_B];
    int t = threadIdx.x;
    int node = blockIdx.x * SCAN_B + t;
    int v = (node < N_NODES) ? counts[node] : 0;
    s[t] = v;
    __syncthreads();
    for (int off = 1; off < SCAN_B; off <<= 1) {
        int u = (t >= off) ? s[t - off] : 0;
        __syncthreads();
        s[t] += u;
        __syncthreads();
    }
    if (node < N_NODES) row_ptr[node] = partial[blockIdx.x] + s[t] - v;
    if (node == 0) row_ptr[N_NODES] = N_EDGES;
}

__global__ void fill_csr_kernel(const int* __restrict__ src, const int* __restrict__ dst,
                                const int* __restrict__ row_ptr, int* __restrict__ cursor,
                                int* __restrict__ csr_src) {
    int e = blockIdx.x * blockDim.x + threadIdx.x;
    if (e < N_EDGES) {
        int d = dst[e];
        int pos = atomicAdd(&cursor[d], 1);
        csr_src[row_ptr[d] + pos] = src[e];
    }
}

// ---------------- casts ----------------

// x fp32 -> bf16, both row-major (for edge gather) and swizzled (for GEMM A-frags)
__global__ void cast_f2b_kernel(const float* __restrict__ in,
                                unsigned short* __restrict__ out_row,
                                unsigned short* __restrict__ out_swz) {
    int i = blockIdx.x * blockDim.x + threadIdx.x;
    if (i * 4 < N_NODES * IN_DIM) {
        float4 v = ((const float4*)in)[i];
        ushort4 o;
        o.x = f2b(v.x); o.y = f2b(v.y); o.z = f2b(v.z); o.w = f2b(v.w);
        ((ushort4*)out_row)[i] = o;
        int m = i >> 5;             // row (128 elems = 32 float4)
        int kb = (i & 31) * 4;      // col base
        *(ushort4*)(out_swz + swz(m, kb, IN_DIM)) = o;  // kb&7 in {0,4}: 4 elems contiguous
    }
}

// all four weight transposes in one launch, output swizzled [n][k] panels
__global__ void tcast4_kernel(const float* __restrict__ W1l, const float* __restrict__ W1r,
                              const float* __restrict__ W2l, const float* __restrict__ W2r,
                              unsigned short* __restrict__ W1lt, unsigned short* __restrict__ W1rt,
                              unsigned short* __restrict__ W2lt, unsigned short* __restrict__ W2rt) {
    int i = blockIdx.x * blockDim.x + threadIdx.x;
    const float* in; unsigned short* out; int K, base;
    if (i < 32768)        { in = W1l; out = W1lt; K = IN_DIM; base = 0; }
    else if (i < 65536)   { in = W1r; out = W1rt; K = IN_DIM; base = 32768; }
    else if (i < 131072)  { in = W2l; out = W2lt; K = HID;    base = 65536; }
    else if (i < 196608)  { in = W2r; out = W2rt; K = HID;    base = 131072; }
    else return;
    int j = i - base;
    int k = j >> 8;              // N == 256
    int n = j & 255;
    out[swz(n, k, K)] = f2b(in[j]);
}

// out[m][c] = bh[c]
__global__ void init_out_kernel(const float* __restrict__ bh, float* __restrict__ out) {
    int i = blockIdx.x * blockDim.x + threadIdx.x;
    if (i < N_NODES * 3) out[i] = bh[i % 3];
}

// ---------------- mean aggregation: row-major gather, swizzled store ----------------

static __device__ __forceinline__ void addv(float* acc, uint4 v) {
    acc[0] += b2f((unsigned short)(v.x & 0xffff));
    acc[1] += b2f((unsigned short)(v.x >> 16));
    acc[2] += b2f((unsigned short)(v.y & 0xffff));
    acc[3] += b2f((unsigned short)(v.y >> 16));
    acc[4] += b2f((unsigned short)(v.z & 0xffff));
    acc[5] += b2f((unsigned short)(v.z >> 16));
    acc[6] += b2f((unsigned short)(v.w & 0xffff));
    acc[7] += b2f((unsigned short)(v.w >> 16));
}

static __device__ __forceinline__ uint4 pack8(const float* a) {
    uint4 pk;
    pk.x = (unsigned)f2b(a[0]) | ((unsigned)f2b(a[1]) << 16);
    pk.y = (unsigned)f2b(a[2]) | ((unsigned)f2b(a[3]) << 16);
    pk.z = (unsigned)f2b(a[4]) | ((unsigned)f2b(a[5]) << 16);
    pk.w = (unsigned)f2b(a[6]) | ((unsigned)f2b(a[7]) << 16);
    return pk;
}

// D=256: gather row-major feat, write swizzled mean (K=256 panel)
__global__ __launch_bounds__(256) void agg_mean256_kernel(const unsigned short* __restrict__ feat,
                                                          const int* __restrict__ row_ptr,
                                                          const int* __restrict__ csr_src,
                                                          unsigned short* __restrict__ out_swz) {
    int node = blockIdx.x * 4 + (threadIdx.x >> 6);
    if (node >= N_NODES) return;
    int lane = threadIdx.x & 63;
    int half = lane >> 5, lh = lane & 31;
    const uint4* f4 = (const uint4*)feat;  // row stride 32 uint4
    float acc[8];
#pragma unroll
    for (int j = 0; j < 8; j++) acc[j] = 0.f;
    int beg = row_ptr[node], end = row_ptr[node + 1];
    int i = beg;
    for (; i + 4 <= end; i += 4) {
        int sA = csr_src[i + half];
        int sB = csr_src[i + 2 + half];
        uint4 vA = f4[(size_t)sA * 32 + lh];
        uint4 vB = f4[(size_t)sB * 32 + lh];
        addv(acc, vA);
        addv(acc, vB);
    }
    if (i + 2 <= end) {
        int s = csr_src[i + half];
        addv(acc, f4[(size_t)s * 32 + lh]);
        i += 2;
    }
    if (i < end && half == 0) {
        int s = csr_src[i];
        addv(acc, f4[(size_t)s * 32 + lh]);
    }
    float inv = (end > beg) ? 1.0f / (float)(end - beg) : 0.0f;
#pragma unroll
    for (int j = 0; j < 8; j++) {
        acc[j] += __shfl_xor(acc[j], 32);
        acc[j] *= inv;
    }
    // lane lh holds elems k = lh*8 .. lh*8+7 of row `node`
    if (half == 0) *(uint4*)(out_swz + swz(node, lh * 8, HID)) = pack8(acc);
}

// D=128: gather row-major feat, write swizzled mean (K=128 panel)
__global__ __launch_bounds__(256) void agg_mean128_kernel(const unsigned short* __restrict__ feat,
                                                          const int* __restrict__ row_ptr,
                                                          const int* __restrict__ csr_src,
                                                          unsigned short* __restrict__ out_swz) {
    int node = blockIdx.x * 4 + (threadIdx.x >> 6);
    if (node >= N_NODES) return;
    int lane = threadIdx.x & 63;
    int q = lane >> 4, lq = lane & 15;
    const uint4* f4 = (const uint4*)feat;  // row stride 16 uint4
    float acc[8];
#pragma unroll
    for (int j = 0; j < 8; j++) acc[j] = 0.f;
    int beg = row_ptr[node], end = row_ptr[node + 1];
    int i = beg;
    for (; i + 8 <= end; i += 8) {
        int sA = csr_src[i + q];
        int sB = csr_src[i + 4 + q];
        uint4 vA = f4[(size_t)sA * 16 + lq];
        uint4 vB = f4[(size_t)sB * 16 + lq];
        addv(acc, vA);
        addv(acc, vB);
    }
    if (i + 4 <= end) {
        int s = csr_src[i + q];
        addv(acc, f4[(size_t)s * 16 + lq]);
        i += 4;
    }
    int rem = end - i;
    if (q < rem) {
        int s = csr_src[i + q];
        addv(acc, f4[(size_t)s * 16 + lq]);
    }
    float inv = (end > beg) ? 1.0f / (float)(end - beg) : 0.0f;
#pragma unroll
    for (int j = 0; j < 8; j++) {
        acc[j] += __shfl_xor(acc[j], 32);
        acc[j] += __shfl_xor(acc[j], 16);
        acc[j] *= inv;
    }
    if (q == 0) *(uint4*)(out_swz + swz(node, lq * 8, IN_DIM)) = pack8(acc);
}

// ---------------- zero-LDS zero-barrier pipelined GEMM on swizzled panels ----------------
// Block = 4 waves; wave w computes rows [m0+w*32,+32) x 64 cols (n-slice by blockIdx.x,
// n fastest-varying so the 4 n-slices of one A panel dispatch adjacently -> L2/L3 reuse).
// acc = 32 VGPRs; explicit 2-deep pipeline (tile t+1 loads issued before tile t MFMAs)
// fits in VGPR budget -> loads genuinely in flight. No LDS, no barriers.

template <int KP>  // per-phase K: 128 (layer1) or 256 (layer2)
static __device__ __forceinline__ void gemm_swz_core64(
    const unsigned short* __restrict__ A0, const unsigned short* __restrict__ B0,
    const unsigned short* __restrict__ A1, const unsigned short* __restrict__ B1,
    int tmw, int tn0, int l, f32x4 (&acc)[2][4]) {
    constexpr int KT = KP / 32;
    constexpr int TT = 2 * KT;
    bf16x8 a[2][2], b[2][4];

#define LDTILE(t_, s_)                                                                     \
    {                                                                                      \
        const unsigned short* A_ = ((t_) < KT) ? A0 : A1;                                  \
        const unsigned short* B_ = ((t_) < KT) ? B0 : B1;                                  \
        const int tk_ = ((t_) < KT) ? (t_) : (t_) - KT;                                    \
        a[s_][0] = *(const bf16x8*)(A_ + ((((size_t)tmw) * KT + tk_) << 9) + l * 8);       \
        a[s_][1] = *(const bf16x8*)(A_ + ((((size_t)(tmw + 1)) * KT + tk_) << 9) + l * 8); \
        _Pragma("unroll")                                                                  \
        for (int nt = 0; nt < 4; nt++)                                                     \
            b[s_][nt] = *(const bf16x8*)(B_ + ((((size_t)(tn0 + nt)) * KT + tk_) << 9) + l * 8); \
    }

    LDTILE(0, 0)
#pragma unroll
    for (int t = 0; t < TT; t++) {
        const int cur = t & 1;
        if (t + 1 < TT) LDTILE(t + 1, cur ^ 1)
#pragma unroll
        for (int mt = 0; mt < 2; mt++)
#pragma unroll
            for (int nt = 0; nt < 4; nt++)
                acc[mt][nt] = __builtin_amdgcn_mfma_f32_16x16x32_bf16(a[cur][mt], b[cur][nt],
                                                                      acc[mt][nt], 0, 0, 0);
    }
#undef LDTILE
}

// layer 1: h1 = relu(A0@W0 + A1@W1 + bias); writes h1 row-major AND swizzled(K=256)
template <int KP>
__global__ __launch_bounds__(256) void gemm_swz_kernel(
    const unsigned short* __restrict__ A0, const unsigned short* __restrict__ B0,
    const unsigned short* __restrict__ A1, const unsigned short* __restrict__ B1,
    const float* __restrict__ bias, unsigned short* __restrict__ out_row,
    unsigned short* __restrict__ out_swz, int M) {
    const int t = threadIdx.x;
    const int w = t >> 6, l = t & 63;
    const int quad = l >> 4, lr = l & 15;
    const int n0 = blockIdx.x * 64, m0 = blockIdx.y * 128;
    const int tmw = (m0 >> 4) + w * 2, tn0 = n0 >> 4;

    f32x4 acc[2][4];
    const f32x4 zero = {0.f, 0.f, 0.f, 0.f};
#pragma unroll
    for (int mt = 0; mt < 2; mt++)
#pragma unroll
        for (int nt = 0; nt < 4; nt++) acc[mt][nt] = zero;

    float bias_r[4];
#pragma unroll
    for (int nt = 0; nt < 4; nt++) bias_r[nt] = bias[n0 + nt * 16 + lr];

    gemm_swz_core64<KP>(A0, B0, A1, B1, tmw, tn0, l, acc);

#pragma unroll
    for (int mt = 0; mt < 2; mt++)
#pragma unroll
        for (int r = 0; r < 4; r++) {
            int gm = m0 + w * 32 + mt * 16 + quad * 4 + r;
            if (gm >= M) continue;
            unsigned short* orow = out_row + (size_t)gm * HID;
#pragma unroll
            for (int nt = 0; nt < 4; nt++) {
                int gn = n0 + nt * 16 + lr;
                unsigned short h = f2b(fmaxf(acc[mt][nt][r] + bias_r[nt], 0.f));
                orow[gn] = h;
                out_swz[swz(gm, gn, HID)] = h;
            }
        }
}

// layer 2 + head: out += sum_n relu(gemm)*Wh  (out pre-init to bh)
template <int KP>
__global__ __launch_bounds__(256) void gemm_swz_head_kernel(
    const unsigned short* __restrict__ A0, const unsigned short* __restrict__ B0,
    const unsigned short* __restrict__ A1, const unsigned short* __restrict__ B1,
    const float* __restrict__ bias, const float* __restrict__ Wh,
    float* __restrict__ out, int M) {
    const int t = threadIdx.x;
    const int w = t >> 6, l = t & 63;
    const int quad = l >> 4, lr = l & 15;
    const int n0 = blockIdx.x * 64, m0 = blockIdx.y * 128;
    const int tmw = (m0 >> 4) + w * 2, tn0 = n0 >> 4;

    f32x4 acc[2][4];
    const f32x4 zero = {0.f, 0.f, 0.f, 0.f};
#pragma unroll
    for (int mt = 0; mt < 2; mt++)
#pragma unroll
        for (int nt = 0; nt < 4; nt++) acc[mt][nt] = zero;

    float bias_r[4];
    float wh_r[4][3];
#pragma unroll
    for (int nt = 0; nt < 4; nt++) {
        int gn = n0 + nt * 16 + lr;
        bias_r[nt] = bias[gn];
        wh_r[nt][0] = Wh[gn * 3 + 0];
        wh_r[nt][1] = Wh[gn * 3 + 1];
        wh_r[nt][2] = Wh[gn * 3 + 2];
    }

    gemm_swz_core64<KP>(A0, B0, A1, B1, tmw, tn0, l, acc);

#pragma unroll
    for (int mt = 0; mt < 2; mt++)
#pragma unroll
        for (int r = 0; r < 4; r++) {
            int gm = m0 + w * 32 + mt * 16 + quad * 4 + r;
            float p0 = 0.f, p1 = 0.f, p2 = 0.f;
#pragma unroll
            for (int nt = 0; nt < 4; nt++) {
                float v = fmaxf(acc[mt][nt][r] + bias_r[nt], 0.f);
                p0 += v * wh_r[nt][0];
                p1 += v * wh_r[nt][1];
                p2 += v * wh_r[nt][2];
            }
#pragma unroll
            for (int off = 1; off < 16; off <<= 1) {
                p0 += __shfl_xor(p0, off);
                p1 += __shfl_xor(p1, off);
                p2 += __shfl_xor(p2, off);
            }
            if (lr == 0 && gm < M) {
                atomicAdd(&out[(size_t)gm * 3 + 0], p0);
                atomicAdd(&out[(size_t)gm * 3 + 1], p1);
                atomicAdd(&out[(size_t)gm * 3 + 2], p2);
            }
        }
}

// ---------------- launch ----------------

extern "C" void kernel_launch(void* const* d_in, const int* in_sizes, int n_in,
                              void* d_out, int out_size, void* d_ws, size_t ws_size,
                              hipStream_t stream) {
    const float* x   = (const float*)d_in[0];
    const int*   ei  = (const int*)d_in[1];
    const int*   src = ei;
    const int*   dst = ei + N_EDGES;
    const float* W1l = (const float*)d_in[2];
    const float* b1  = (const float*)d_in[3];
    const float* W1r = (const float*)d_in[4];
    const float* W2l = (const float*)d_in[5];
    const float* b2  = (const float*)d_in[6];
    const float* W2r = (const float*)d_in[7];
    const float* Wh  = (const float*)d_in[8];
    const float* bh  = (const float*)d_in[9];
    float* out = (float*)d_out;

    char* ws = (char*)d_ws;
    size_t off = 0;
    auto alloc = [&](size_t bytes) -> void* {
        void* p = ws + off;
        off = (off + bytes + 255) & ~(size_t)255;
        return p;
    };
    int* counts   = (int*)alloc((size_t)N_NODES * 4);
    int* row_ptr  = (int*)alloc((size_t)(N_NODES + 1) * 4);
    int* cursor   = (int*)alloc((size_t)N_NODES * 4);
    int* partial  = (int*)alloc((size_t)SCAN_NB * 4);
    int* csr_src  = (int*)alloc((size_t)N_EDGES * 4);
    unsigned short* xb_row  = (unsigned short*)alloc((size_t)M_PAD * IN_DIM * 2);
    unsigned short* xb_swz  = (unsigned short*)alloc((size_t)M_PAD * IN_DIM * 2);
    unsigned short* agg1    = (unsigned short*)alloc((size_t)M_PAD * IN_DIM * 2);  // swizzled
    unsigned short* h1_row  = (unsigned short*)alloc((size_t)M_PAD * HID * 2);
    unsigned short* h1_swz  = (unsigned short*)alloc((size_t)M_PAD * HID * 2);
    unsigned short* agg2    = (unsigned short*)alloc((size_t)M_PAD * HID * 2);     // swizzled
    unsigned short* W1lt = (unsigned short*)alloc((size_t)IN_DIM * HID * 2);
    unsigned short* W1rt = (unsigned short*)alloc((size_t)IN_DIM * HID * 2);
    unsigned short* W2lt = (unsigned short*)alloc((size_t)HID * HID * 2);
    unsigned short* W2rt = (unsigned short*)alloc((size_t)HID * HID * 2);

    hipMemsetAsync(counts, 0, (size_t)N_NODES * 4, stream);
    hipMemsetAsync(cursor, 0, (size_t)N_NODES * 4, stream);

    const int eblocks = (N_EDGES + 255) / 256;
    count_deg_kernel<<<eblocks, 256, 0, stream>>>(dst, counts);
    block_sum_kernel<<<SCAN_NB, SCAN_B, 0, stream>>>(counts, partial);
    scan_partial_kernel<<<1, SCAN_B, 0, stream>>>(partial);
    write_rowptr_kernel<<<SCAN_NB, SCAN_B, 0, stream>>>(counts, partial, row_ptr);
    fill_csr_kernel<<<eblocks, 256, 0, stream>>>(src, dst, row_ptr, cursor, csr_src);

    // casts (independent of CSR)
    {
        int n = N_NODES * IN_DIM;
        cast_f2b_kernel<<<(n / 4 + 255) / 256, 256, 0, stream>>>(x, xb_row, xb_swz);
        tcast4_kernel<<<(196608 + 255) / 256, 256, 0, stream>>>(W1l, W1r, W2l, W2r,
                                                                W1lt, W1rt, W2lt, W2rt);
        init_out_kernel<<<(N_NODES * 3 + 255) / 256, 256, 0, stream>>>(bh, out);
    }

    const int nblocks4 = (N_NODES + 3) / 4;
    dim3 gg(4, M_PAD / 128);  // n-slice fastest -> A-panel reuse across adjacent blocks

    // layer 1
    agg_mean128_kernel<<<nblocks4, 256, 0, stream>>>(xb_row, row_ptr, csr_src, agg1);
    gemm_swz_kernel<IN_DIM><<<gg, 256, 0, stream>>>(agg1, W1lt, xb_swz, W1rt, b1,
                                                    h1_row, h1_swz, N_NODES);

    // layer 2 + head fused
    agg_mean256_kernel<<<nblocks4, 256, 0, stream>>>(h1_row, row_ptr, csr_src, agg2);
    gemm_swz_head_kernel<HID><<<gg, 256, 0, stream>>>(agg2, W2lt, h1_swz, W2rt, b2, Wh,
                                                      out, N_NODES);
}

// Round 11
// 302.101 us; speedup vs baseline: 1.0326x; 1.0326x over previous
//
#include <hip/hip_runtime.h>
#include <hip/hip_bf16.h>

#define N_NODES 50000
#define N_EDGES 600000
#define IN_DIM 128
#define HID 256
#define OUT_DIM 3

#define M_PAD 50048  // 391 panels * 128 rows
#define N_PANELS 391

#define SCAN_B 256
#define SCAN_NB ((N_NODES + SCAN_B - 1) / SCAN_B)  // 196

typedef __bf16 bf16x8 __attribute__((ext_vector_type(8)));
typedef float f32x4 __attribute__((ext_vector_type(4)));

static __device__ __forceinline__ unsigned short f2b(float f) {
    union { float f; unsigned u; } u; u.f = f;
    unsigned r = u.u + 0x7fffu + ((u.u >> 16) & 1u);  // round-to-nearest-even
    return (unsigned short)(r >> 16);
}
static __device__ __forceinline__ float b2f(unsigned short b) {
    union { unsigned u; float f; } u; u.u = ((unsigned)b) << 16;
    return u.f;
}

// MFMA-fragment ("swizzled") panel layout, K columns:
// tiles of 16 rows x 32 k; tile(tr=r>>4, tk=k>>5) at ((tr*(K/32)+tk)*512) elems;
// element (r,k) within tile at ((k>>3)&3)*128 + (r&15)*8 + (k&7).
// A wave's mfma fragment (one tile) = contiguous 1KB, lane l at tile_base + l*8.
static __device__ __forceinline__ size_t swz(int r, int k, int K) {
    return (((size_t)((r >> 4) * (K >> 5) + (k >> 5))) << 9)
         + ((((k >> 3) & 3) * 16 + (r & 15)) << 3) + (k & 7);
}

// ---------------- CSR build ----------------

__global__ void count_deg_kernel(const int* __restrict__ dst, int* __restrict__ counts) {
    int e = blockIdx.x * blockDim.x + threadIdx.x;
    if (e < N_EDGES) atomicAdd(&counts[dst[e]], 1);
}

__global__ __launch_bounds__(256) void block_sum_kernel(const int* __restrict__ counts,
                                                        int* __restrict__ partial) {
    int node = blockIdx.x * SCAN_B + threadIdx.x;
    int v = (node < N_NODES) ? counts[node] : 0;
#pragma unroll
    for (int off = 32; off > 0; off >>= 1) v += __shfl_down(v, off);
    __shared__ int ws[4];
    if ((threadIdx.x & 63) == 0) ws[threadIdx.x >> 6] = v;
    __syncthreads();
    if (threadIdx.x == 0) partial[blockIdx.x] = ws[0] + ws[1] + ws[2] + ws[3];
}

__global__ __launch_bounds__(256) void scan_partial_kernel(int* __restrict__ partial) {
    __shared__ int s[SCAN_B];
    int t = threadIdx.x;
    int v = (t < SCAN_NB) ? partial[t] : 0;
    s[t] = v;
    __syncthreads();
    for (int off = 1; off < SCAN_B; off <<= 1) {
        int u = (t >= off) ? s[t - off] : 0;
        __syncthreads();
        s[t] += u;
        __syncthreads();
    }
    if (t < SCAN_NB) partial[t] = s[t] - v;  // exclusive
}

__global__ __launch_bounds__(256) void write_rowptr_kernel(const int* __restrict__ counts,
                                                           const int* __restrict__ partial,
                                                           int* __restrict__ row_ptr) {
    __shared__ int s[SCAN_B];
    int t = threadIdx.x;
    int node = blockIdx.x * SCAN_B + t;
    int v = (node < N_NODES) ? counts[node] : 0;
    s[t] = v;
    __syncthreads();
    for (int off = 1; off < SCAN_B; off <<= 1) {
        int u = (t >= off) ? s[t - off] : 0;
        __syncthreads();
        s[t] += u;
        __syncthreads();
    }
    if (node < N_NODES) row_ptr[node] = partial[blockIdx.x] + s[t] - v;
    if (node == 0) row_ptr[N_NODES] = N_EDGES;
}

__global__ void fill_csr_kernel(const int* __restrict__ src, const int* __restrict__ dst,
                                const int* __restrict__ row_ptr, int* __restrict__ cursor,
                                int* __restrict__ csr_src) {
    int e = blockIdx.x * blockDim.x + threadIdx.x;
    if (e < N_EDGES) {
        int d = dst[e];
        int pos = atomicAdd(&cursor[d], 1);
        csr_src[row_ptr[d] + pos] = src[e];
    }
}

// ---------------- casts ----------------

// x fp32 -> bf16, both row-major (for edge gather) and swizzled (for GEMM A-frags)
__global__ void cast_f2b_kernel(const float* __restrict__ in,
                                unsigned short* __restrict__ out_row,
                                unsigned short* __restrict__ out_swz) {
    int i = blockIdx.x * blockDim.x + threadIdx.x;
    if (i * 4 < N_NODES * IN_DIM) {
        float4 v = ((const float4*)in)[i];
        ushort4 o;
        o.x = f2b(v.x); o.y = f2b(v.y); o.z = f2b(v.z); o.w = f2b(v.w);
        ((ushort4*)out_row)[i] = o;
        int m = i >> 5;             // row (128 elems = 32 float4)
        int kb = (i & 31) * 4;      // col base
        *(ushort4*)(out_swz + swz(m, kb, IN_DIM)) = o;  // kb&7 in {0,4}: 4 elems contiguous
    }
}

// all four weight transposes in one launch, output swizzled [n][k] panels
__global__ void tcast4_kernel(const float* __restrict__ W1l, const float* __restrict__ W1r,
                              const float* __restrict__ W2l, const float* __restrict__ W2r,
                              unsigned short* __restrict__ W1lt, unsigned short* __restrict__ W1rt,
                              unsigned short* __restrict__ W2lt, unsigned short* __restrict__ W2rt) {
    int i = blockIdx.x * blockDim.x + threadIdx.x;
    const float* in; unsigned short* out; int K, base;
    if (i < 32768)        { in = W1l; out = W1lt; K = IN_DIM; base = 0; }
    else if (i < 65536)   { in = W1r; out = W1rt; K = IN_DIM; base = 32768; }
    else if (i < 131072)  { in = W2l; out = W2lt; K = HID;    base = 65536; }
    else if (i < 196608)  { in = W2r; out = W2rt; K = HID;    base = 131072; }
    else return;
    int j = i - base;
    int k = j >> 8;              // N == 256
    int n = j & 255;
    out[swz(n, k, K)] = f2b(in[j]);
}

// out[m][c] = bh[c]
__global__ void init_out_kernel(const float* __restrict__ bh, float* __restrict__ out) {
    int i = blockIdx.x * blockDim.x + threadIdx.x;
    if (i < N_NODES * 3) out[i] = bh[i % 3];
}

// ---------------- mean aggregation: row-major gather, swizzled store ----------------

static __device__ __forceinline__ void addv(float* acc, uint4 v) {
    acc[0] += b2f((unsigned short)(v.x & 0xffff));
    acc[1] += b2f((unsigned short)(v.x >> 16));
    acc[2] += b2f((unsigned short)(v.y & 0xffff));
    acc[3] += b2f((unsigned short)(v.y >> 16));
    acc[4] += b2f((unsigned short)(v.z & 0xffff));
    acc[5] += b2f((unsigned short)(v.z >> 16));
    acc[6] += b2f((unsigned short)(v.w & 0xffff));
    acc[7] += b2f((unsigned short)(v.w >> 16));
}

static __device__ __forceinline__ uint4 pack8(const float* a) {
    uint4 pk;
    pk.x = (unsigned)f2b(a[0]) | ((unsigned)f2b(a[1]) << 16);
    pk.y = (unsigned)f2b(a[2]) | ((unsigned)f2b(a[3]) << 16);
    pk.z = (unsigned)f2b(a[4]) | ((unsigned)f2b(a[5]) << 16);
    pk.w = (unsigned)f2b(a[6]) | ((unsigned)f2b(a[7]) << 16);
    return pk;
}

// D=256: gather row-major feat, write swizzled mean (K=256 panel)
__global__ __launch_bounds__(256) void agg_mean256_kernel(const unsigned short* __restrict__ feat,
                                                          const int* __restrict__ row_ptr,
                                                          const int* __restrict__ csr_src,
                                                          unsigned short* __restrict__ out_swz) {
    int node = blockIdx.x * 4 + (threadIdx.x >> 6);
    if (node >= N_NODES) return;
    int lane = threadIdx.x & 63;
    int half = lane >> 5, lh = lane & 31;
    const uint4* f4 = (const uint4*)feat;  // row stride 32 uint4
    float acc[8];
#pragma unroll
    for (int j = 0; j < 8; j++) acc[j] = 0.f;
    int beg = row_ptr[node], end = row_ptr[node + 1];
    int i = beg;
    for (; i + 4 <= end; i += 4) {
        int sA = csr_src[i + half];
        int sB = csr_src[i + 2 + half];
        uint4 vA = f4[(size_t)sA * 32 + lh];
        uint4 vB = f4[(size_t)sB * 32 + lh];
        addv(acc, vA);
        addv(acc, vB);
    }
    if (i + 2 <= end) {
        int s = csr_src[i + half];
        addv(acc, f4[(size_t)s * 32 + lh]);
        i += 2;
    }
    if (i < end && half == 0) {
        int s = csr_src[i];
        addv(acc, f4[(size_t)s * 32 + lh]);
    }
    float inv = (end > beg) ? 1.0f / (float)(end - beg) : 0.0f;
#pragma unroll
    for (int j = 0; j < 8; j++) {
        acc[j] += __shfl_xor(acc[j], 32);
        acc[j] *= inv;
    }
    if (half == 0) *(uint4*)(out_swz + swz(node, lh * 8, HID)) = pack8(acc);
}

// D=128: gather row-major feat, write swizzled mean (K=128 panel)
__global__ __launch_bounds__(256) void agg_mean128_kernel(const unsigned short* __restrict__ feat,
                                                          const int* __restrict__ row_ptr,
                                                          const int* __restrict__ csr_src,
                                                          unsigned short* __restrict__ out_swz) {
    int node = blockIdx.x * 4 + (threadIdx.x >> 6);
    if (node >= N_NODES) return;
    int lane = threadIdx.x & 63;
    int q = lane >> 4, lq = lane & 15;
    const uint4* f4 = (const uint4*)feat;  // row stride 16 uint4
    float acc[8];
#pragma unroll
    for (int j = 0; j < 8; j++) acc[j] = 0.f;
    int beg = row_ptr[node], end = row_ptr[node + 1];
    int i = beg;
    for (; i + 8 <= end; i += 8) {
        int sA = csr_src[i + q];
        int sB = csr_src[i + 4 + q];
        uint4 vA = f4[(size_t)sA * 16 + lq];
        uint4 vB = f4[(size_t)sB * 16 + lq];
        addv(acc, vA);
        addv(acc, vB);
    }
    if (i + 4 <= end) {
        int s = csr_src[i + q];
        addv(acc, f4[(size_t)s * 16 + lq]);
        i += 4;
    }
    int rem = end - i;
    if (q < rem) {
        int s = csr_src[i + q];
        addv(acc, f4[(size_t)s * 16 + lq]);
    }
    float inv = (end > beg) ? 1.0f / (float)(end - beg) : 0.0f;
#pragma unroll
    for (int j = 0; j < 8; j++) {
        acc[j] += __shfl_xor(acc[j], 32);
        acc[j] += __shfl_xor(acc[j], 16);
        acc[j] *= inv;
    }
    if (q == 0) *(uint4*)(out_swz + swz(node, lq * 8, IN_DIM)) = pack8(acc);
}

// ---------------- zero-LDS zero-barrier DEPTH-4 pipelined GEMM on swizzled panels ----------
// 1-D XCD-swizzled grid: bid -> panel=(bid>>5)*8+(bid&7), nslice=(bid>>3)&3, so a panel's
// 4 n-slices share bid%8 == same XCD -> A re-reads hit that XCD's L2.
// Wave computes 32(M) x 64(N); acc = 32 VGPRs. Software pipeline depth 4: loads for step
// t+3 issued in step t (slot arrays a[4][2], b[4][4]) -> per-step stall ~ latency/3.

template <int KP>  // per-phase K: 128 (layer1) or 256 (layer2)
static __device__ __forceinline__ void gemm_swz_core_pd4(
    const unsigned short* __restrict__ A0, const unsigned short* __restrict__ B0,
    const unsigned short* __restrict__ A1, const unsigned short* __restrict__ B1,
    int tmw, int tn0, int l, f32x4 (&acc)[2][4]) {
    constexpr int KT = KP / 32;
    constexpr int TT = 2 * KT;
    bf16x8 a[4][2], b[4][4];

    auto ldtile = [&](int t_, int s_) {
        const unsigned short* A_ = (t_ < KT) ? A0 : A1;
        const unsigned short* B_ = (t_ < KT) ? B0 : B1;
        const int tk_ = (t_ < KT) ? t_ : t_ - KT;
        a[s_][0] = *(const bf16x8*)(A_ + ((((size_t)tmw) * KT + tk_) << 9) + l * 8);
        a[s_][1] = *(const bf16x8*)(A_ + ((((size_t)(tmw + 1)) * KT + tk_) << 9) + l * 8);
#pragma unroll
        for (int nt = 0; nt < 4; nt++)
            b[s_][nt] = *(const bf16x8*)(B_ + ((((size_t)(tn0 + nt)) * KT + tk_) << 9) + l * 8);
    };

#pragma unroll
    for (int p = 0; p < 3; p++) ldtile(p, p);  // preload 3 steps
#pragma unroll
    for (int t = 0; t < TT; t++) {
        const int cur = t & 3;
        if (t + 3 < TT) ldtile(t + 3, (t + 3) & 3);
#pragma unroll
        for (int mt = 0; mt < 2; mt++)
#pragma unroll
            for (int nt = 0; nt < 4; nt++)
                acc[mt][nt] = __builtin_amdgcn_mfma_f32_16x16x32_bf16(a[cur][mt], b[cur][nt],
                                                                      acc[mt][nt], 0, 0, 0);
    }
}

// layer 1: h1 = relu(A0@W0 + A1@W1 + bias); writes h1 row-major AND swizzled(K=256)
template <int KP>
__global__ __launch_bounds__(256, 3) void gemm_swz_kernel(
    const unsigned short* __restrict__ A0, const unsigned short* __restrict__ B0,
    const unsigned short* __restrict__ A1, const unsigned short* __restrict__ B1,
    const float* __restrict__ bias, unsigned short* __restrict__ out_row,
    unsigned short* __restrict__ out_swz, int M) {
    const int bid = blockIdx.x;
    const int panel = (bid >> 5) * 8 + (bid & 7);
    if (panel >= N_PANELS) return;
    const int t = threadIdx.x;
    const int w = t >> 6, l = t & 63;
    const int quad = l >> 4, lr = l & 15;
    const int m0 = panel * 128, n0 = ((bid >> 3) & 3) * 64;
    const int tmw = (m0 >> 4) + w * 2, tn0 = n0 >> 4;

    f32x4 acc[2][4];
    const f32x4 zero = {0.f, 0.f, 0.f, 0.f};
#pragma unroll
    for (int mt = 0; mt < 2; mt++)
#pragma unroll
        for (int nt = 0; nt < 4; nt++) acc[mt][nt] = zero;

    float bias_r[4];
#pragma unroll
    for (int nt = 0; nt < 4; nt++) bias_r[nt] = bias[n0 + nt * 16 + lr];

    gemm_swz_core_pd4<KP>(A0, B0, A1, B1, tmw, tn0, l, acc);

#pragma unroll
    for (int mt = 0; mt < 2; mt++)
#pragma unroll
        for (int r = 0; r < 4; r++) {
            int gm = m0 + w * 32 + mt * 16 + quad * 4 + r;
            if (gm >= M) continue;
            unsigned short* orow = out_row + (size_t)gm * HID;
#pragma unroll
            for (int nt = 0; nt < 4; nt++) {
                int gn = n0 + nt * 16 + lr;
                unsigned short h = f2b(fmaxf(acc[mt][nt][r] + bias_r[nt], 0.f));
                orow[gn] = h;
                out_swz[swz(gm, gn, HID)] = h;
            }
        }
}

// layer 2 + head: out += sum_n relu(gemm)*Wh  (out pre-init to bh)
template <int KP>
__global__ __launch_bounds__(256, 3) void gemm_swz_head_kernel(
    const unsigned short* __restrict__ A0, const unsigned short* __restrict__ B0,
    const unsigned short* __restrict__ A1, const unsigned short* __restrict__ B1,
    const float* __restrict__ bias, const float* __restrict__ Wh,
    float* __restrict__ out, int M) {
    const int bid = blockIdx.x;
    const int panel = (bid >> 5) * 8 + (bid & 7);
    if (panel >= N_PANELS) return;
    const int t = threadIdx.x;
    const int w = t >> 6, l = t & 63;
    const int quad = l >> 4, lr = l & 15;
    const int m0 = panel * 128, n0 = ((bid >> 3) & 3) * 64;
    const int tmw = (m0 >> 4) + w * 2, tn0 = n0 >> 4;

    f32x4 acc[2][4];
    const f32x4 zero = {0.f, 0.f, 0.f, 0.f};
#pragma unroll
    for (int mt = 0; mt < 2; mt++)
#pragma unroll
        for (int nt = 0; nt < 4; nt++) acc[mt][nt] = zero;

    float bias_r[4];
    float wh_r[4][3];
#pragma unroll
    for (int nt = 0; nt < 4; nt++) {
        int gn = n0 + nt * 16 + lr;
        bias_r[nt] = bias[gn];
        wh_r[nt][0] = Wh[gn * 3 + 0];
        wh_r[nt][1] = Wh[gn * 3 + 1];
        wh_r[nt][2] = Wh[gn * 3 + 2];
    }

    gemm_swz_core_pd4<KP>(A0, B0, A1, B1, tmw, tn0, l, acc);

#pragma unroll
    for (int mt = 0; mt < 2; mt++)
#pragma unroll
        for (int r = 0; r < 4; r++) {
            int gm = m0 + w * 32 + mt * 16 + quad * 4 + r;
            float p0 = 0.f, p1 = 0.f, p2 = 0.f;
#pragma unroll
            for (int nt = 0; nt < 4; nt++) {
                float v = fmaxf(acc[mt][nt][r] + bias_r[nt], 0.f);
                p0 += v * wh_r[nt][0];
                p1 += v * wh_r[nt][1];
                p2 += v * wh_r[nt][2];
            }
#pragma unroll
            for (int off = 1; off < 16; off <<= 1) {
                p0 += __shfl_xor(p0, off);
                p1 += __shfl_xor(p1, off);
                p2 += __shfl_xor(p2, off);
            }
            if (lr == 0 && gm < M) {
                atomicAdd(&out[(size_t)gm * 3 + 0], p0);
                atomicAdd(&out[(size_t)gm * 3 + 1], p1);
                atomicAdd(&out[(size_t)gm * 3 + 2], p2);
            }
        }
}

// ---------------- launch ----------------

extern "C" void kernel_launch(void* const* d_in, const int* in_sizes, int n_in,
                              void* d_out, int out_size, void* d_ws, size_t ws_size,
                              hipStream_t stream) {
    const float* x   = (const float*)d_in[0];
    const int*   ei  = (const int*)d_in[1];
    const int*   src = ei;
    const int*   dst = ei + N_EDGES;
    const float* W1l = (const float*)d_in[2];
    const float* b1  = (const float*)d_in[3];
    const float* W1r = (const float*)d_in[4];
    const float* W2l = (const float*)d_in[5];
    const float* b2  = (const float*)d_in[6];
    const float* W2r = (const float*)d_in[7];
    const float* Wh  = (const float*)d_in[8];
    const float* bh  = (const float*)d_in[9];
    float* out = (float*)d_out;

    char* ws = (char*)d_ws;
    size_t off = 0;
    auto alloc = [&](size_t bytes) -> void* {
        void* p = ws + off;
        off = (off + bytes + 255) & ~(size_t)255;
        return p;
    };
    int* counts   = (int*)alloc((size_t)N_NODES * 4);
    int* row_ptr  = (int*)alloc((size_t)(N_NODES + 1) * 4);
    int* cursor   = (int*)alloc((size_t)N_NODES * 4);
    int* partial  = (int*)alloc((size_t)SCAN_NB * 4);
    int* csr_src  = (int*)alloc((size_t)N_EDGES * 4);
    unsigned short* xb_row  = (unsigned short*)alloc((size_t)M_PAD * IN_DIM * 2);
    unsigned short* xb_swz  = (unsigned short*)alloc((size_t)M_PAD * IN_DIM * 2);
    unsigned short* agg1    = (unsigned short*)alloc((size_t)M_PAD * IN_DIM * 2);  // swizzled
    unsigned short* h1_row  = (unsigned short*)alloc((size_t)M_PAD * HID * 2);
    unsigned short* h1_swz  = (unsigned short*)alloc((size_t)M_PAD * HID * 2);
    unsigned short* agg2    = (unsigned short*)alloc((size_t)M_PAD * HID * 2);     // swizzled
    unsigned short* W1lt = (unsigned short*)alloc((size_t)IN_DIM * HID * 2);
    unsigned short* W1rt = (unsigned short*)alloc((size_t)IN_DIM * HID * 2);
    unsigned short* W2lt = (unsigned short*)alloc((size_t)HID * HID * 2);
    unsigned short* W2rt = (unsigned short*)alloc((size_t)HID * HID * 2);

    hipMemsetAsync(counts, 0, (size_t)N_NODES * 4, stream);
    hipMemsetAsync(cursor, 0, (size_t)N_NODES * 4, stream);

    const int eblocks = (N_EDGES + 255) / 256;
    count_deg_kernel<<<eblocks, 256, 0, stream>>>(dst, counts);
    block_sum_kernel<<<SCAN_NB, SCAN_B, 0, stream>>>(counts, partial);
    scan_partial_kernel<<<1, SCAN_B, 0, stream>>>(partial);
    write_rowptr_kernel<<<SCAN_NB, SCAN_B, 0, stream>>>(counts, partial, row_ptr);
    fill_csr_kernel<<<eblocks, 256, 0, stream>>>(src, dst, row_ptr, cursor, csr_src);

    // casts (independent of CSR)
    {
        int n = N_NODES * IN_DIM;
        cast_f2b_kernel<<<(n / 4 + 255) / 256, 256, 0, stream>>>(x, xb_row, xb_swz);
        tcast4_kernel<<<(196608 + 255) / 256, 256, 0, stream>>>(W1l, W1r, W2l, W2r,
                                                                W1lt, W1rt, W2lt, W2rt);
        init_out_kernel<<<(N_NODES * 3 + 255) / 256, 256, 0, stream>>>(bh, out);
    }

    const int nblocks4 = (N_NODES + 3) / 4;
    const int gemm_blocks = ((N_PANELS + 7) / 8) * 32;  // 49 groups * 32 = 1568

    // layer 1
    agg_mean128_kernel<<<nblocks4, 256, 0, stream>>>(xb_row, row_ptr, csr_src, agg1);
    gemm_swz_kernel<IN_DIM><<<gemm_blocks, 256, 0, stream>>>(agg1, W1lt, xb_swz, W1rt, b1,
                                                             h1_row, h1_swz, N_NODES);

    // layer 2 + head fused
    agg_mean256_kernel<<<nblocks4, 256, 0, stream>>>(h1_row, row_ptr, csr_src, agg2);
    gemm_swz_head_kernel<HID><<<gemm_blocks, 256, 0, stream>>>(agg2, W2lt, h1_swz, W2rt, b2, Wh,
                                                               out, N_NODES);
}

// Round 12
// 298.260 us; speedup vs baseline: 1.0459x; 1.0129x over previous
//
#include <hip/hip_runtime.h>
#include <hip/hip_bf16.h>

#define N_NODES 50000
#define N_EDGES 600000
#define IN_DIM 128
#define HID 256
#define OUT_DIM 3

#define M_PAD 50048  // 391 panels * 128 rows
#define N_PANELS 391

#define SCAN_B 256
#define SCAN_NB ((N_NODES + SCAN_B - 1) / SCAN_B)  // 196

typedef __bf16 bf16x8 __attribute__((ext_vector_type(8)));
typedef float f32x4 __attribute__((ext_vector_type(4)));

static __device__ __forceinline__ unsigned short f2b(float f) {
    union { float f; unsigned u; } u; u.f = f;
    unsigned r = u.u + 0x7fffu + ((u.u >> 16) & 1u);  // round-to-nearest-even
    return (unsigned short)(r >> 16);
}
static __device__ __forceinline__ float b2f(unsigned short b) {
    union { unsigned u; float f; } u; u.u = ((unsigned)b) << 16;
    return u.f;
}

// MFMA-fragment ("swizzled") panel layout, K columns:
// tiles of 16 rows x 32 k; tile(tr=r>>4, tk=k>>5) at ((tr*(K/32)+tk)*512) elems;
// element (r,k) within tile at ((k>>3)&3)*128 + (r&15)*8 + (k&7).
// A wave's mfma fragment (one tile) = contiguous 1KB, lane l at tile_base + l*8.
static __device__ __forceinline__ size_t swz(int r, int k, int K) {
    return (((size_t)((r >> 4) * (K >> 5) + (k >> 5))) << 9)
         + ((((k >> 3) & 3) * 16 + (r & 15)) << 3) + (k & 7);
}

// ---------------- CSR build ----------------

__global__ void count_deg_kernel(const int* __restrict__ dst, int* __restrict__ counts) {
    int e = blockIdx.x * blockDim.x + threadIdx.x;
    if (e < N_EDGES) atomicAdd(&counts[dst[e]], 1);
}

__global__ __launch_bounds__(256) void block_sum_kernel(const int* __restrict__ counts,
                                                        int* __restrict__ partial) {
    int node = blockIdx.x * SCAN_B + threadIdx.x;
    int v = (node < N_NODES) ? counts[node] : 0;
#pragma unroll
    for (int off = 32; off > 0; off >>= 1) v += __shfl_down(v, off);
    __shared__ int ws[4];
    if ((threadIdx.x & 63) == 0) ws[threadIdx.x >> 6] = v;
    __syncthreads();
    if (threadIdx.x == 0) partial[blockIdx.x] = ws[0] + ws[1] + ws[2] + ws[3];
}

__global__ __launch_bounds__(256) void scan_partial_kernel(int* __restrict__ partial) {
    __shared__ int s[SCAN_B];
    int t = threadIdx.x;
    int v = (t < SCAN_NB) ? partial[t] : 0;
    s[t] = v;
    __syncthreads();
    for (int off = 1; off < SCAN_B; off <<= 1) {
        int u = (t >= off) ? s[t - off] : 0;
        __syncthreads();
        s[t] += u;
        __syncthreads();
    }
    if (t < SCAN_NB) partial[t] = s[t] - v;  // exclusive
}

__global__ __launch_bounds__(256) void write_rowptr_kernel(const int* __restrict__ counts,
                                                           const int* __restrict__ partial,
                                                           int* __restrict__ row_ptr) {
    __shared__ int s[SCAN_B];
    int t = threadIdx.x;
    int node = blockIdx.x * SCAN_B + t;
    int v = (node < N_NODES) ? counts[node] : 0;
    s[t] = v;
    __syncthreads();
    for (int off = 1; off < SCAN_B; off <<= 1) {
        int u = (t >= off) ? s[t - off] : 0;
        __syncthreads();
        s[t] += u;
        __syncthreads();
    }
    if (node < N_NODES) row_ptr[node] = partial[blockIdx.x] + s[t] - v;
    if (node == 0) row_ptr[N_NODES] = N_EDGES;
}

__global__ void fill_csr_kernel(const int* __restrict__ src, const int* __restrict__ dst,
                                const int* __restrict__ row_ptr, int* __restrict__ cursor,
                                int* __restrict__ csr_src) {
    int e = blockIdx.x * blockDim.x + threadIdx.x;
    if (e < N_EDGES) {
        int d = dst[e];
        int pos = atomicAdd(&cursor[d], 1);
        csr_src[row_ptr[d] + pos] = src[e];
    }
}

// ---------------- fused prep: cast x (row+swz), weight transposes (swz), init out ---------

#define PREP_X (N_NODES * IN_DIM / 4)            // 1600000
#define PREP_W (PREP_X + 196608)
#define PREP_O (PREP_W + N_NODES * 3)

__global__ void prep_kernel(const float* __restrict__ x,
                            const float* __restrict__ W1l, const float* __restrict__ W1r,
                            const float* __restrict__ W2l, const float* __restrict__ W2r,
                            const float* __restrict__ bh,
                            unsigned short* __restrict__ xb_row,
                            unsigned short* __restrict__ xb_swz,
                            unsigned short* __restrict__ W1lt, unsigned short* __restrict__ W1rt,
                            unsigned short* __restrict__ W2lt, unsigned short* __restrict__ W2rt,
                            float* __restrict__ out) {
    int i = blockIdx.x * blockDim.x + threadIdx.x;
    if (i < PREP_X) {
        float4 v = ((const float4*)x)[i];
        ushort4 o;
        o.x = f2b(v.x); o.y = f2b(v.y); o.z = f2b(v.z); o.w = f2b(v.w);
        ((ushort4*)xb_row)[i] = o;
        int m = i >> 5;             // row (128 elems = 32 float4)
        int kb = (i & 31) * 4;      // col base
        *(ushort4*)(xb_swz + swz(m, kb, IN_DIM)) = o;
    } else if (i < PREP_W) {
        int j = i - PREP_X;
        const float* in; unsigned short* outw; int K;
        if (j < 32768)       { in = W1l; outw = W1lt; K = IN_DIM; }
        else if (j < 65536)  { in = W1r; outw = W1rt; K = IN_DIM; j -= 32768; }
        else if (j < 131072) { in = W2l; outw = W2lt; K = HID;    j -= 65536; }
        else                 { in = W2r; outw = W2rt; K = HID;    j -= 131072; }
        int k = j >> 8;              // N == 256
        int n = j & 255;
        outw[swz(n, k, K)] = f2b(in[j]);
    } else if (i < PREP_O) {
        int j = i - PREP_W;
        out[j] = bh[j % 3];
    }
}

// ---------------- mean aggregation: row-major gather, swizzled store ----------------

static __device__ __forceinline__ void addv(float* acc, uint4 v) {
    acc[0] += b2f((unsigned short)(v.x & 0xffff));
    acc[1] += b2f((unsigned short)(v.x >> 16));
    acc[2] += b2f((unsigned short)(v.y & 0xffff));
    acc[3] += b2f((unsigned short)(v.y >> 16));
    acc[4] += b2f((unsigned short)(v.z & 0xffff));
    acc[5] += b2f((unsigned short)(v.z >> 16));
    acc[6] += b2f((unsigned short)(v.w & 0xffff));
    acc[7] += b2f((unsigned short)(v.w >> 16));
}

static __device__ __forceinline__ uint4 pack8(const float* a) {
    uint4 pk;
    pk.x = (unsigned)f2b(a[0]) | ((unsigned)f2b(a[1]) << 16);
    pk.y = (unsigned)f2b(a[2]) | ((unsigned)f2b(a[3]) << 16);
    pk.z = (unsigned)f2b(a[4]) | ((unsigned)f2b(a[5]) << 16);
    pk.w = (unsigned)f2b(a[6]) | ((unsigned)f2b(a[7]) << 16);
    return pk;
}

// D=256: gather row-major feat, write swizzled mean (K=256 panel)
__global__ __launch_bounds__(256) void agg_mean256_kernel(const unsigned short* __restrict__ feat,
                                                          const int* __restrict__ row_ptr,
                                                          const int* __restrict__ csr_src,
                                                          unsigned short* __restrict__ out_swz) {
    int node = blockIdx.x * 4 + (threadIdx.x >> 6);
    if (node >= N_NODES) return;
    int lane = threadIdx.x & 63;
    int half = lane >> 5, lh = lane & 31;
    const uint4* f4 = (const uint4*)feat;  // row stride 32 uint4
    float acc[8];
#pragma unroll
    for (int j = 0; j < 8; j++) acc[j] = 0.f;
    int beg = row_ptr[node], end = row_ptr[node + 1];
    int i = beg;
    for (; i + 4 <= end; i += 4) {
        int sA = csr_src[i + half];
        int sB = csr_src[i + 2 + half];
        uint4 vA = f4[(size_t)sA * 32 + lh];
        uint4 vB = f4[(size_t)sB * 32 + lh];
        addv(acc, vA);
        addv(acc, vB);
    }
    if (i + 2 <= end) {
        int s = csr_src[i + half];
        addv(acc, f4[(size_t)s * 32 + lh]);
        i += 2;
    }
    if (i < end && half == 0) {
        int s = csr_src[i];
        addv(acc, f4[(size_t)s * 32 + lh]);
    }
    float inv = (end > beg) ? 1.0f / (float)(end - beg) : 0.0f;
#pragma unroll
    for (int j = 0; j < 8; j++) {
        acc[j] += __shfl_xor(acc[j], 32);
        acc[j] *= inv;
    }
    if (half == 0) *(uint4*)(out_swz + swz(node, lh * 8, HID)) = pack8(acc);
}

// D=128: gather row-major feat, write swizzled mean (K=128 panel)
__global__ __launch_bounds__(256) void agg_mean128_kernel(const unsigned short* __restrict__ feat,
                                                          const int* __restrict__ row_ptr,
                                                          const int* __restrict__ csr_src,
                                                          unsigned short* __restrict__ out_swz) {
    int node = blockIdx.x * 4 + (threadIdx.x >> 6);
    if (node >= N_NODES) return;
    int lane = threadIdx.x & 63;
    int q = lane >> 4, lq = lane & 15;
    const uint4* f4 = (const uint4*)feat;  // row stride 16 uint4
    float acc[8];
#pragma unroll
    for (int j = 0; j < 8; j++) acc[j] = 0.f;
    int beg = row_ptr[node], end = row_ptr[node + 1];
    int i = beg;
    for (; i + 8 <= end; i += 8) {
        int sA = csr_src[i + q];
        int sB = csr_src[i + 4 + q];
        uint4 vA = f4[(size_t)sA * 16 + lq];
        uint4 vB = f4[(size_t)sB * 16 + lq];
        addv(acc, vA);
        addv(acc, vB);
    }
    if (i + 4 <= end) {
        int s = csr_src[i + q];
        addv(acc, f4[(size_t)s * 16 + lq]);
        i += 4;
    }
    int rem = end - i;
    if (q < rem) {
        int s = csr_src[i + q];
        addv(acc, f4[(size_t)s * 16 + lq]);
    }
    float inv = (end > beg) ? 1.0f / (float)(end - beg) : 0.0f;
#pragma unroll
    for (int j = 0; j < 8; j++) {
        acc[j] += __shfl_xor(acc[j], 32);
        acc[j] += __shfl_xor(acc[j], 16);
        acc[j] *= inv;
    }
    if (q == 0) *(uint4*)(out_swz + swz(node, lq * 8, IN_DIM)) = pack8(acc);
}

// ---------------- GEMM: LDS-resident B slice, barrier-free K-loop, depth-4 A prefetch -------
// 1-D XCD-swizzled grid: bid -> panel=(bid>>5)*8+(bid&7), nslice=(bid>>3)&3 -> same-XCD
// A-panel reuse. Per phase: stage this block's 64-col B slice (contiguous in the swizzled
// panel) into LDS ONCE (one barrier), then run the whole K-loop with ZERO barriers:
// A fragments direct from global (coalesced 1KB wave-loads, depth-4 VGPR pipeline),
// B fragments from LDS (no L2 re-fetch amplification). 3 barriers total per kernel.

template <int KP>  // per-phase K: 128 (layer1) or 256 (layer2)
static __device__ __forceinline__ void gemm_lds_core(
    const unsigned short* __restrict__ A0, const unsigned short* __restrict__ B0,
    const unsigned short* __restrict__ A1, const unsigned short* __restrict__ B1,
    unsigned short* Bl,  // 64*KP elems
    int tmw, int tn0, int t, int l, f32x4 (&acc)[2][4]) {
    constexpr int KT = KP / 32;

    for (int p = 0; p < 2; p++) {
        const unsigned short* A = p ? A1 : A0;
        const unsigned short* B = p ? B1 : B0;
        if (p) __syncthreads();  // prior phase's B reads done
        {   // stage B slice: contiguous 4*KT*512 elems starting at tile tn0*KT
            const uint4* srcp = (const uint4*)(B + (((size_t)tn0 * KT) << 9));
            uint4* dstp = (uint4*)Bl;
            constexpr int TOT = 4 * KT * 64;  // uint4 count
#pragma unroll
            for (int i = 0; i < TOT / 256; i++) dstp[i * 256 + t] = srcp[i * 256 + t];
        }
        __syncthreads();

        bf16x8 a[4][2];
        auto lda = [&](int tk, int s) {
            a[s][0] = *(const bf16x8*)(A + ((((size_t)tmw) * KT + tk) << 9) + l * 8);
            a[s][1] = *(const bf16x8*)(A + ((((size_t)(tmw + 1)) * KT + tk) << 9) + l * 8);
        };
#pragma unroll
        for (int q = 0; q < 3 && q < KT; q++) lda(q, q);
#pragma unroll
        for (int tk = 0; tk < KT; tk++) {
            const int cur = tk & 3;
            if (tk + 3 < KT) lda(tk + 3, (tk + 3) & 3);
            bf16x8 b[4];
#pragma unroll
            for (int nt = 0; nt < 4; nt++)
                b[nt] = *(const bf16x8*)&Bl[((((size_t)nt) * KT + tk) << 9) + l * 8];
#pragma unroll
            for (int mt = 0; mt < 2; mt++)
#pragma unroll
                for (int nt = 0; nt < 4; nt++)
                    acc[mt][nt] = __builtin_amdgcn_mfma_f32_16x16x32_bf16(a[cur][mt], b[nt],
                                                                          acc[mt][nt], 0, 0, 0);
        }
    }
}

// layer 1: h1 = relu(A0@W0 + A1@W1 + bias); writes h1 row-major AND swizzled(K=256)
template <int KP>
__global__ __launch_bounds__(256) void gemm_lds_kernel(
    const unsigned short* __restrict__ A0, const unsigned short* __restrict__ B0,
    const unsigned short* __restrict__ A1, const unsigned short* __restrict__ B1,
    const float* __restrict__ bias, unsigned short* __restrict__ out_row,
    unsigned short* __restrict__ out_swz, int M) {
    __shared__ __align__(16) unsigned short Bl[64 * KP];
    const int bid = blockIdx.x;
    const int panel = (bid >> 5) * 8 + (bid & 7);
    if (panel >= N_PANELS) return;
    const int t = threadIdx.x;
    const int w = t >> 6, l = t & 63;
    const int quad = l >> 4, lr = l & 15;
    const int m0 = panel * 128, n0 = ((bid >> 3) & 3) * 64;
    const int tmw = (m0 >> 4) + w * 2, tn0 = n0 >> 4;

    f32x4 acc[2][4];
    const f32x4 zero = {0.f, 0.f, 0.f, 0.f};
#pragma unroll
    for (int mt = 0; mt < 2; mt++)
#pragma unroll
        for (int nt = 0; nt < 4; nt++) acc[mt][nt] = zero;

    float bias_r[4];
#pragma unroll
    for (int nt = 0; nt < 4; nt++) bias_r[nt] = bias[n0 + nt * 16 + lr];

    gemm_lds_core<KP>(A0, B0, A1, B1, Bl, tmw, tn0, t, l, acc);

#pragma unroll
    for (int mt = 0; mt < 2; mt++)
#pragma unroll
        for (int r = 0; r < 4; r++) {
            int gm = m0 + w * 32 + mt * 16 + quad * 4 + r;
            if (gm >= M) continue;
            unsigned short* orow = out_row + (size_t)gm * HID;
#pragma unroll
            for (int nt = 0; nt < 4; nt++) {
                int gn = n0 + nt * 16 + lr;
                unsigned short h = f2b(fmaxf(acc[mt][nt][r] + bias_r[nt], 0.f));
                orow[gn] = h;
                out_swz[swz(gm, gn, HID)] = h;
            }
        }
}

// layer 2 + head: out += sum_n relu(gemm)*Wh  (out pre-init to bh)
template <int KP>
__global__ __launch_bounds__(256) void gemm_lds_head_kernel(
    const unsigned short* __restrict__ A0, const unsigned short* __restrict__ B0,
    const unsigned short* __restrict__ A1, const unsigned short* __restrict__ B1,
    const float* __restrict__ bias, const float* __restrict__ Wh,
    float* __restrict__ out, int M) {
    __shared__ __align__(16) unsigned short Bl[64 * KP];
    const int bid = blockIdx.x;
    const int panel = (bid >> 5) * 8 + (bid & 7);
    if (panel >= N_PANELS) return;
    const int t = threadIdx.x;
    const int w = t >> 6, l = t & 63;
    const int quad = l >> 4, lr = l & 15;
    const int m0 = panel * 128, n0 = ((bid >> 3) & 3) * 64;
    const int tmw = (m0 >> 4) + w * 2, tn0 = n0 >> 4;

    f32x4 acc[2][4];
    const f32x4 zero = {0.f, 0.f, 0.f, 0.f};
#pragma unroll
    for (int mt = 0; mt < 2; mt++)
#pragma unroll
        for (int nt = 0; nt < 4; nt++) acc[mt][nt] = zero;

    float bias_r[4];
    float wh_r[4][3];
#pragma unroll
    for (int nt = 0; nt < 4; nt++) {
        int gn = n0 + nt * 16 + lr;
        bias_r[nt] = bias[gn];
        wh_r[nt][0] = Wh[gn * 3 + 0];
        wh_r[nt][1] = Wh[gn * 3 + 1];
        wh_r[nt][2] = Wh[gn * 3 + 2];
    }

    gemm_lds_core<KP>(A0, B0, A1, B1, Bl, tmw, tn0, t, l, acc);

#pragma unroll
    for (int mt = 0; mt < 2; mt++)
#pragma unroll
        for (int r = 0; r < 4; r++) {
            int gm = m0 + w * 32 + mt * 16 + quad * 4 + r;
            float p0 = 0.f, p1 = 0.f, p2 = 0.f;
#pragma unroll
            for (int nt = 0; nt < 4; nt++) {
                float v = fmaxf(acc[mt][nt][r] + bias_r[nt], 0.f);
                p0 += v * wh_r[nt][0];
                p1 += v * wh_r[nt][1];
                p2 += v * wh_r[nt][2];
            }
#pragma unroll
            for (int off = 1; off < 16; off <<= 1) {
                p0 += __shfl_xor(p0, off);
                p1 += __shfl_xor(p1, off);
                p2 += __shfl_xor(p2, off);
            }
            if (lr == 0 && gm < M) {
                atomicAdd(&out[(size_t)gm * 3 + 0], p0);
                atomicAdd(&out[(size_t)gm * 3 + 1], p1);
                atomicAdd(&out[(size_t)gm * 3 + 2], p2);
            }
        }
}

// ---------------- launch ----------------

extern "C" void kernel_launch(void* const* d_in, const int* in_sizes, int n_in,
                              void* d_out, int out_size, void* d_ws, size_t ws_size,
                              hipStream_t stream) {
    const float* x   = (const float*)d_in[0];
    const int*   ei  = (const int*)d_in[1];
    const int*   src = ei;
    const int*   dst = ei + N_EDGES;
    const float* W1l = (const float*)d_in[2];
    const float* b1  = (const float*)d_in[3];
    const float* W1r = (const float*)d_in[4];
    const float* W2l = (const float*)d_in[5];
    const float* b2  = (const float*)d_in[6];
    const float* W2r = (const float*)d_in[7];
    const float* Wh  = (const float*)d_in[8];
    const float* bh  = (const float*)d_in[9];
    float* out = (float*)d_out;

    char* ws = (char*)d_ws;
    size_t off = 0;
    auto alloc = [&](size_t bytes) -> void* {
        void* p = ws + off;
        off = (off + bytes + 255) & ~(size_t)255;
        return p;
    };
    int* counts   = (int*)alloc((size_t)N_NODES * 4);
    int* row_ptr  = (int*)alloc((size_t)(N_NODES + 1) * 4);
    int* cursor   = (int*)alloc((size_t)N_NODES * 4);
    int* partial  = (int*)alloc((size_t)SCAN_NB * 4);
    int* csr_src  = (int*)alloc((size_t)N_EDGES * 4);
    unsigned short* xb_row  = (unsigned short*)alloc((size_t)M_PAD * IN_DIM * 2);
    unsigned short* xb_swz  = (unsigned short*)alloc((size_t)M_PAD * IN_DIM * 2);
    unsigned short* agg1    = (unsigned short*)alloc((size_t)M_PAD * IN_DIM * 2);  // swizzled
    unsigned short* h1_row  = (unsigned short*)alloc((size_t)M_PAD * HID * 2);
    unsigned short* h1_swz  = (unsigned short*)alloc((size_t)M_PAD * HID * 2);
    unsigned short* agg2    = (unsigned short*)alloc((size_t)M_PAD * HID * 2);     // swizzled
    unsigned short* W1lt = (unsigned short*)alloc((size_t)IN_DIM * HID * 2);
    unsigned short* W1rt = (unsigned short*)alloc((size_t)IN_DIM * HID * 2);
    unsigned short* W2lt = (unsigned short*)alloc((size_t)HID * HID * 2);
    unsigned short* W2rt = (unsigned short*)alloc((size_t)HID * HID * 2);

    hipMemsetAsync(counts, 0, (size_t)N_NODES * 4, stream);
    hipMemsetAsync(cursor, 0, (size_t)N_NODES * 4, stream);

    const int eblocks = (N_EDGES + 255) / 256;
    count_deg_kernel<<<eblocks, 256, 0, stream>>>(dst, counts);
    block_sum_kernel<<<SCAN_NB, SCAN_B, 0, stream>>>(counts, partial);
    scan_partial_kernel<<<1, SCAN_B, 0, stream>>>(partial);
    write_rowptr_kernel<<<SCAN_NB, SCAN_B, 0, stream>>>(counts, partial, row_ptr);
    fill_csr_kernel<<<eblocks, 256, 0, stream>>>(src, dst, row_ptr, cursor, csr_src);

    // fused prep (independent of CSR)
    prep_kernel<<<(PREP_O + 255) / 256, 256, 0, stream>>>(x, W1l, W1r, W2l, W2r, bh,
                                                          xb_row, xb_swz,
                                                          W1lt, W1rt, W2lt, W2rt, out);

    const int nblocks4 = (N_NODES + 3) / 4;
    const int gemm_blocks = ((N_PANELS + 7) / 8) * 32;  // 49 groups * 32 = 1568

    // layer 1
    agg_mean128_kernel<<<nblocks4, 256, 0, stream>>>(xb_row, row_ptr, csr_src, agg1);
    gemm_lds_kernel<IN_DIM><<<gemm_blocks, 256, 0, stream>>>(agg1, W1lt, xb_swz, W1rt, b1,
                                                             h1_row, h1_swz, N_NODES);

    // layer 2 + head fused
    agg_mean256_kernel<<<nblocks4, 256, 0, stream>>>(h1_row, row_ptr, csr_src, agg2);
    gemm_lds_head_kernel<HID><<<gemm_blocks, 256, 0, stream>>>(agg2, W2lt, h1_swz, W2rt, b2, Wh,
                                                               out, N_NODES);
}